// Round 6
// baseline (16.018 us; speedup 1.0000x reference)
//
#include <hip/hip_runtime.h>
#include <hip/hip_fp16.h>

#define B 4
#define CIN 64
#define OC 64
#define LMAX 144
#define HP 34
#define WP 34
#define HPW (HP*WP)            // 1156
#define NPIX 1024
#define RSTR 34                // row stride in half2 units (paired layout)
#define NPR 18                 // paired rows per channel: pr holds rows (pr, pr+16)
#define CSTR (NPR*RSTR)        // 612 half2 per channel
#define GUARD 4                // guard half2 slots at front
#define TOT_H2 (GUARD + CIN*CSTR)   // 39,172 half2 = 156,688 B

// One block per (b,o), 512 threads, 2 px/thread (rows h0, h0+16).
// Paired-row f16 layout: s_img[GUARD + c*612 + pr*34 + col] is a half2
// holding padded rows (pr, pr+16) at physical col = padded col - 1.
// R6 change vs R5: taps live in per-lane VGPRs (loaded once from global,
// decomposed pre-loop); the fully-unrolled gather uses v_readlane to get
// each tap's (offset, weight) into SGPRs -- zero DS ops for taps, leaving
// exactly one ds_read_b32 per tap per thread.
__global__ __launch_bounds__(512, 1) void reconv_rl(
    const float* __restrict__ images,
    const int* __restrict__ tap_idx, const float* __restrict__ tap_w,
    const int* __restrict__ bias_index, const float* __restrict__ bias_value,
    float* __restrict__ out)
{
    __shared__ unsigned int s_img[TOT_H2];   // half2 per slot

    const int bo = blockIdx.x;
    const int b = bo >> 6;                   // / OC
    const int o = bo & (OC - 1);
    const int t = threadIdx.x;
    const int lane = t & 63;

    // --- Per-wave tap preload: lane l holds taps l, 64+l, 128+(l&15) ---
    const int* ti = tap_idx + o * LMAX;
    const float* tw = tap_w + o * LMAX;
    int vidx0 = ti[lane];
    int vidx1 = ti[64 + lane];
    int vidx2 = ti[128 + (lane & 15)];       // clamped: stays inside this o's row
    int vw0 = __float_as_int(tw[lane]);
    int vw1 = __float_as_int(tw[64 + lane]);
    int vw2 = __float_as_int(tw[128 + (lane & 15)]);

    // decompose idx -> packed LDS byte offset (per-lane VALU, one-time)
    int voff0, voff1, voff2;
    {
        int c0 = vidx0 / HPW, r0 = vidx0 - c0 * HPW, kh0 = r0 / WP, kw0 = r0 - kh0 * WP;
        voff0 = (GUARD + c0 * CSTR + kh0 * RSTR + kw0 - 1) * 4;
        int c1 = vidx1 / HPW, r1 = vidx1 - c1 * HPW, kh1 = r1 / WP, kw1 = r1 - kh1 * WP;
        voff1 = (GUARD + c1 * CSTR + kh1 * RSTR + kw1 - 1) * 4;
        int c2 = vidx2 / HPW, r2 = vidx2 - c2 * HPW, kh2 = r2 / WP, kw2 = r2 - kh2 * WP;
        voff2 = (GUARD + c2 * CSTR + kh2 * RSTR + kw2 - 1) * 4;
    }

    unsigned long long* s64 = (unsigned long long*)s_img;

    // --- Zero: guard + physical cols 32,33 of every (c,pr) ---
    if (t == 0) { s64[0] = 0ull; s64[1] = 0ull; }
    for (int i = t; i < CIN * NPR; i += 512) {
        int c = i / NPR;
        int pr = i - c * NPR;
        int e = GUARD + c * CSTR + pr * RSTR + 32;      // e even -> 8B aligned
        *(unsigned long long*)&s_img[e] = 0ull;
    }

    // --- Bias (general scatter-add semantics, uniform scalar work) ---
    float bias = 0.f;
    for (int i = 0; i < OC; ++i)
        bias += (bias_index[i] == o) ? bias_value[i] : 0.f;

    // --- Stage interior: image rows (ir, ir+16) packed as half2 ---
    const float4* img4 = (const float4*)images + (size_t)b * (CIN * 32 * 32 / 4);
    const int q = t & 7;                     // float4 index within a 32-col row
    const int g = t >> 3;                    // 0..63
    #pragma unroll 4
    for (int i = 0; i < 16; ++i) {
        int rowid = i * 64 + g;              // 0..1023
        int c = rowid >> 4;
        int ir = rowid & 15;
        float4 a = img4[c * 256 + ir * 8 + q];
        float4 d = img4[c * 256 + (ir + 16) * 8 + q];
        unsigned int u0 = ((unsigned)__half_as_ushort(__float2half(d.x)) << 16) | __half_as_ushort(__float2half(a.x));
        unsigned int u1 = ((unsigned)__half_as_ushort(__float2half(d.y)) << 16) | __half_as_ushort(__float2half(a.y));
        unsigned int u2 = ((unsigned)__half_as_ushort(__float2half(d.z)) << 16) | __half_as_ushort(__float2half(a.z));
        unsigned int u3 = ((unsigned)__half_as_ushort(__float2half(d.w)) << 16) | __half_as_ushort(__float2half(a.w));
        int e = GUARD + c * CSTR + (ir + 1) * RSTR + 4 * q;   // e even -> 8B aligned
        *(unsigned long long*)&s_img[e]     = ((unsigned long long)u1 << 32) | u0;
        *(unsigned long long*)&s_img[e + 2] = ((unsigned long long)u3 << 32) | u2;
    }
    // Specials: pr=0 = {pad0, img row 15}; pr=17 = {img row 16, pad33}.
    for (int i = t; i < CIN * 8 * 2; i += 512) {
        int c = i >> 4;
        int r2 = i & 15;
        int which = r2 >> 3;                 // 0 -> pr=0, 1 -> pr=17
        int qq = r2 & 7;
        float4 v = img4[c * 256 + (which ? 16 : 15) * 8 + qq];
        unsigned int u0, u1, u2, u3;
        if (which == 0) {                    // lo = 0 (padded row 0), hi = img15
            u0 = (unsigned)__half_as_ushort(__float2half(v.x)) << 16;
            u1 = (unsigned)__half_as_ushort(__float2half(v.y)) << 16;
            u2 = (unsigned)__half_as_ushort(__float2half(v.z)) << 16;
            u3 = (unsigned)__half_as_ushort(__float2half(v.w)) << 16;
        } else {                             // lo = img16, hi = 0 (padded row 33)
            u0 = __half_as_ushort(__float2half(v.x));
            u1 = __half_as_ushort(__float2half(v.y));
            u2 = __half_as_ushort(__float2half(v.z));
            u3 = __half_as_ushort(__float2half(v.w));
        }
        int e = GUARD + c * CSTR + (which ? 17 : 0) * RSTR + 4 * qq;
        *(unsigned long long*)&s_img[e]     = ((unsigned long long)u1 << 32) | u0;
        *(unsigned long long*)&s_img[e + 2] = ((unsigned long long)u3 << 32) | u2;
    }

    __syncthreads();

    // --- Gather: 1 ds_read_b32 per tap; taps via v_readlane (no DS) ---
    const int w = t & 31;
    const int h0 = t >> 5;                   // 0..15
    const int pxb = (h0 * RSTR + w) * 4;     // thread's byte addend
    const char* sbase = (const char*)s_img;
    float a0 = 0.f, a1 = 0.f;
    #pragma unroll
    for (int j = 0; j < LMAX; ++j) {
        int rsel, ln;
        if (j < 64)       { rsel = 0; ln = j; }
        else if (j < 128) { rsel = 1; ln = j - 64; }
        else              { rsel = 2; ln = j - 128; }
        int vo = (rsel == 0) ? voff0 : (rsel == 1) ? voff1 : voff2;
        int vw = (rsel == 0) ? vw0   : (rsel == 1) ? vw1   : vw2;
        int soff = __builtin_amdgcn_readlane(vo, ln);   // uniform SGPR
        int swb  = __builtin_amdgcn_readlane(vw, ln);
        __half2 hv = *(const __half2*)(sbase + (soff + pxb));
        float wgt = __int_as_float(swb);
        a0 = fmaf(wgt, __low2float(hv), a0);
        a1 = fmaf(wgt, __high2float(hv), a1);
    }

    float* op = out + (size_t)bo * NPIX;
    op[h0 * 32 + w] = a0 + bias;
    op[(h0 + 16) * 32 + w] = a1 + bias;
}

extern "C" void kernel_launch(void* const* d_in, const int* in_sizes, int n_in,
                              void* d_out, int out_size, void* d_ws, size_t ws_size,
                              hipStream_t stream) {
    const float* images     = (const float*)d_in[0];
    const int*   tap_idx    = (const int*)d_in[1];
    const float* tap_w      = (const float*)d_in[2];
    const int*   bias_index = (const int*)d_in[3];
    const float* bias_value = (const float*)d_in[4];
    float* out = (float*)d_out;

    reconv_rl<<<B * OC, 512, 0, stream>>>(images, tap_idx, tap_w,
                                          bias_index, bias_value, out);
}

// Round 7
// 12.411 us; speedup vs baseline: 1.2907x; 1.2907x over previous
//
#include <hip/hip_runtime.h>
#include <hip/hip_fp16.h>

#define B 4
#define CIN 64
#define OC 64
#define LMAX 144
#define HP 34
#define WP 34
#define HPW (HP*WP)            // 1156
#define NPIX 1024
#define RSTR 34                // row stride in half2 units (paired layout)
#define NPR 18                 // paired rows per channel: pr holds rows (pr, pr+16)
#define CSTR (NPR*RSTR)        // 612 half2 per channel
#define GUARD 4                // guard half2 slots at front
#define TOT_H2 (GUARD + CIN*CSTR)   // 39,172 half2 = 156,688 B

typedef _Float16 h2_t __attribute__((ext_vector_type(2)));
typedef unsigned long long u64;

static __device__ __forceinline__ unsigned pk(float lo, float hi) {
    return __builtin_bit_cast(unsigned, __builtin_amdgcn_cvt_pkrtz(lo, hi));
}

// One block per (b,o), 512 threads, 2 px/thread (rows h0, h0+16).
// Paired-row f16 layout: s_img[GUARD + c*612 + pr*34 + col] is a half2
// holding padded rows (pr, pr+16) at physical col = padded col - 1; the
// kw-1+w = -1 underflow lands in the previous slot's zeroed col (or guard).
// R7 vs R6: v_cvt_pkrtz_f16_f32 packing (1 op per pair), wave-parallel
// bias via __shfl_xor, loads issued before dependent VALU phases.
__global__ __launch_bounds__(512, 1) void reconv_r7(
    const float* __restrict__ images,
    const int* __restrict__ tap_idx, const float* __restrict__ tap_w,
    const int* __restrict__ bias_index, const float* __restrict__ bias_value,
    float* __restrict__ out)
{
    __shared__ unsigned int s_img[TOT_H2];   // half2 per slot

    const int bo = blockIdx.x;
    const int b = bo >> 6;                   // / OC
    const int o = bo & (OC - 1);
    const int t = threadIdx.x;
    const int lane = t & 63;

    // --- Tap preload (issue these global loads first) ---
    const int* ti = tap_idx + o * LMAX;
    const float* tw = tap_w + o * LMAX;
    int vidx0 = ti[lane];
    int vidx1 = ti[64 + lane];
    int vidx2 = ti[128 + (lane & 15)];
    int vw0 = __float_as_int(tw[lane]);
    int vw1 = __float_as_int(tw[64 + lane]);
    int vw2 = __float_as_int(tw[128 + (lane & 15)]);

    // --- Bias: wave-parallel (OC == 64 == wave width) ---
    float bv = (bias_index[lane] == o) ? bias_value[lane] : 0.f;
    bv += __shfl_xor(bv, 32); bv += __shfl_xor(bv, 16); bv += __shfl_xor(bv, 8);
    bv += __shfl_xor(bv, 4);  bv += __shfl_xor(bv, 2);  bv += __shfl_xor(bv, 1);
    const float bias = bv;

    // --- Stage interior: image rows (ir, ir+16) packed as half2 via pkrtz ---
    const float4* img4 = (const float4*)images + (size_t)b * (CIN * 32 * 32 / 4);
    const int q = t & 7;                     // float4 index within a 32-col row
    const int g = t >> 3;                    // 0..63
    #pragma unroll 4
    for (int i = 0; i < 16; ++i) {
        int rowid = i * 64 + g;              // 0..1023
        int c = rowid >> 4;
        int ir = rowid & 15;
        float4 a = img4[c * 256 + ir * 8 + q];
        float4 d = img4[c * 256 + (ir + 16) * 8 + q];
        unsigned u0 = pk(a.x, d.x);
        unsigned u1 = pk(a.y, d.y);
        unsigned u2 = pk(a.z, d.z);
        unsigned u3 = pk(a.w, d.w);
        int e = GUARD + c * CSTR + (ir + 1) * RSTR + 4 * q;   // even -> 8B aligned
        *(u64*)&s_img[e]     = ((u64)u1 << 32) | u0;
        *(u64*)&s_img[e + 2] = ((u64)u3 << 32) | u2;
    }
    // Specials: pr=0 = {pad0, img row 15}; pr=17 = {img row 16, pad33}.
    for (int i = t; i < CIN * 8 * 2; i += 512) {
        int c = i >> 4;
        int r2 = i & 15;
        int which = r2 >> 3;                 // 0 -> pr=0, 1 -> pr=17
        int qq = r2 & 7;
        float4 v = img4[c * 256 + (which ? 16 : 15) * 8 + qq];
        unsigned u0 = which ? pk(v.x, 0.f) : pk(0.f, v.x);
        unsigned u1 = which ? pk(v.y, 0.f) : pk(0.f, v.y);
        unsigned u2 = which ? pk(v.z, 0.f) : pk(0.f, v.z);
        unsigned u3 = which ? pk(v.w, 0.f) : pk(0.f, v.w);
        int e = GUARD + c * CSTR + (which ? 17 : 0) * RSTR + 4 * qq;
        *(u64*)&s_img[e]     = ((u64)u1 << 32) | u0;
        *(u64*)&s_img[e + 2] = ((u64)u3 << 32) | u2;
    }

    // --- Tap decompose: idx -> packed LDS byte offset (per-lane VALU) ---
    int voff0, voff1, voff2;
    {
        int c0 = vidx0 / HPW, r0 = vidx0 - c0 * HPW, kh0 = r0 / WP, kw0 = r0 - kh0 * WP;
        voff0 = (GUARD + c0 * CSTR + kh0 * RSTR + kw0 - 1) * 4;
        int c1 = vidx1 / HPW, r1 = vidx1 - c1 * HPW, kh1 = r1 / WP, kw1 = r1 - kh1 * WP;
        voff1 = (GUARD + c1 * CSTR + kh1 * RSTR + kw1 - 1) * 4;
        int c2 = vidx2 / HPW, r2 = vidx2 - c2 * HPW, kh2 = r2 / WP, kw2 = r2 - kh2 * WP;
        voff2 = (GUARD + c2 * CSTR + kh2 * RSTR + kw2 - 1) * 4;
    }

    // --- Zero: guard + physical cols 32,33 of every (c,pr) (disjoint from interior) ---
    u64* s64 = (u64*)s_img;
    if (t == 0) { s64[0] = 0ull; s64[1] = 0ull; }
    for (int i = t; i < CIN * NPR; i += 512) {
        int c = i / NPR;
        int pr = i - c * NPR;
        int e = GUARD + c * CSTR + pr * RSTR + 32;      // even -> 8B aligned
        *(u64*)&s_img[e] = 0ull;
    }

    __syncthreads();

    // --- Gather: 1 ds_read_b32 per tap; taps via v_readlane (no DS, no SMEM) ---
    const int w = t & 31;
    const int h0 = t >> 5;                   // 0..15
    const int pxb = (h0 * RSTR + w) * 4;     // thread's byte addend
    const char* sbase = (const char*)s_img;
    float a0 = 0.f, a1 = 0.f;
    #pragma unroll
    for (int j = 0; j < LMAX; ++j) {
        int vo, vw;
        if (j < 64)       { vo = __builtin_amdgcn_readlane(voff0, j);
                            vw = __builtin_amdgcn_readlane(vw0, j); }
        else if (j < 128) { vo = __builtin_amdgcn_readlane(voff1, j - 64);
                            vw = __builtin_amdgcn_readlane(vw1, j - 64); }
        else              { vo = __builtin_amdgcn_readlane(voff2, j - 128);
                            vw = __builtin_amdgcn_readlane(vw2, j - 128); }
        __half2 hv = *(const __half2*)(sbase + (vo + pxb));
        float wgt = __int_as_float(vw);
        a0 = fmaf(wgt, __low2float(hv), a0);
        a1 = fmaf(wgt, __high2float(hv), a1);
    }

    float* op = out + (size_t)bo * NPIX;
    op[h0 * 32 + w] = a0 + bias;
    op[(h0 + 16) * 32 + w] = a1 + bias;
}

extern "C" void kernel_launch(void* const* d_in, const int* in_sizes, int n_in,
                              void* d_out, int out_size, void* d_ws, size_t ws_size,
                              hipStream_t stream) {
    const float* images     = (const float*)d_in[0];
    const int*   tap_idx    = (const int*)d_in[1];
    const float* tap_w      = (const float*)d_in[2];
    const int*   bias_index = (const int*)d_in[3];
    const float* bias_value = (const float*)d_in[4];
    float* out = (float*)d_out;

    reconv_r7<<<B * OC, 512, 0, stream>>>(images, tap_idx, tap_w,
                                          bias_index, bias_value, out);
}